// Round 1
// baseline (217.619 us; speedup 1.0000x reference)
//
#include <hip/hip_runtime.h>

#define EPS 1e-5f

constexpr int B = 32;
constexpr int H = 512;
constexpr int W = 512;
constexpr int NPIX = H * W;          // 262144
constexpr int P = 13;
constexpr int HP = H - P + 1;        // 500
constexpr int WP = W - P + 1;        // 500
constexpr int TILES_X = 8;           // 8 * 64 = 512 >= 500 output cols
constexpr int BANDS_Y = 4;           // 4 * 125 = 500 output rows
constexpr int BAND_ROWS = 125;

// ws layout (floats): gs[5][B] global moment sums, then ps[B] patch cc sums
// total = 6*32 floats = 768 bytes

// ---------------------------------------------------------------------------
// Kernel A: global moment sums per batch (5 quantities), float4 loads.
// grid = B*8 blocks, 256 threads. Each block does 32768 elems of one batch.
// ---------------------------------------------------------------------------
__global__ __launch_bounds__(256) void global_stats_kernel(
    const float* __restrict__ x1, const float* __restrict__ x2,
    float* __restrict__ gs) {
  int b = blockIdx.x >> 3;
  int chunk = blockIdx.x & 7;
  int tid = threadIdx.x;

  const float4* p1 = (const float4*)x1 + (size_t)b * (NPIX / 4) + chunk * 8192;
  const float4* p2 = (const float4*)x2 + (size_t)b * (NPIX / 4) + chunk * 8192;

  float s1 = 0.f, s2 = 0.f, s11 = 0.f, s22 = 0.f, s12 = 0.f;
#pragma unroll 4
  for (int i = 0; i < 32; ++i) {
    float4 a = p1[i * 256 + tid];
    float4 c = p2[i * 256 + tid];
    s1 += a.x + a.y + a.z + a.w;
    s2 += c.x + c.y + c.z + c.w;
    s11 = fmaf(a.x, a.x, fmaf(a.y, a.y, fmaf(a.z, a.z, fmaf(a.w, a.w, s11))));
    s22 = fmaf(c.x, c.x, fmaf(c.y, c.y, fmaf(c.z, c.z, fmaf(c.w, c.w, s22))));
    s12 = fmaf(a.x, c.x, fmaf(a.y, c.y, fmaf(a.z, c.z, fmaf(a.w, c.w, s12))));
  }

  // wave (64-lane) reduction, then cross-wave via LDS
  float v[5] = {s1, s2, s11, s22, s12};
  __shared__ float red[5][4];
#pragma unroll
  for (int k = 0; k < 5; ++k) {
#pragma unroll
    for (int off = 32; off > 0; off >>= 1) v[k] += __shfl_down(v[k], off, 64);
  }
  int lane = tid & 63;
  int wave = tid >> 6;
  if (lane == 0) {
#pragma unroll
    for (int k = 0; k < 5; ++k) red[k][wave] = v[k];
  }
  __syncthreads();
  if (tid == 0) {
#pragma unroll
    for (int k = 0; k < 5; ++k) {
      float t = red[k][0] + red[k][1] + red[k][2] + red[k][3];
      atomicAdd(&gs[k * B + b], t);
    }
  }
}

// ---------------------------------------------------------------------------
// Kernel B: patch NCC. One block = (batch, 64-col tile, 125-row band).
// Per row-step: stage 76 floats of each input row in LDS, each thread forms
// 13-tap horizontal sums of 5 quantities, vertical sliding sum via 13-deep
// LDS ring buffer, accumulate cc in-register.
// grid = B * TILES_X * BANDS_Y = 1024 blocks, 64 threads.
// ---------------------------------------------------------------------------
__global__ __launch_bounds__(64) void patch_kernel(
    const float* __restrict__ x1, const float* __restrict__ x2,
    float* __restrict__ ps) {
  int b = blockIdx.x >> 5;
  int rem = blockIdx.x & 31;
  int tile = rem & 7;
  int band = rem >> 3;
  int x0 = tile * 64;
  int y0 = band * BAND_ROWS;
  int tid = threadIdx.x;
  int x = x0 + tid;
  bool valid = (x < WP);

  __shared__ float ra[76];
  __shared__ float rb[76];
  __shared__ float ring[5][13][64];

  const float* base1 = x1 + (size_t)b * NPIX;
  const float* base2 = x2 + (size_t)b * NPIX;

  float S1 = 0.f, S2 = 0.f, S11 = 0.f, S22 = 0.f, S12 = 0.f;
  float acc = 0.f;
  const float inv_n = 1.0f / 169.0f;

  for (int t = 0; t < BAND_ROWS + P - 1; ++t) {  // 137 input rows
    int yy = y0 + t;
    {
      int c = x0 + tid;
      if (c > W - 1) c = W - 1;
      ra[tid] = base1[yy * W + c];
      rb[tid] = base2[yy * W + c];
      if (tid < 12) {
        int c2 = x0 + 64 + tid;
        if (c2 > W - 1) c2 = W - 1;
        ra[64 + tid] = base1[yy * W + c2];
        rb[64 + tid] = base2[yy * W + c2];
      }
    }
    __syncthreads();

    float h1 = 0.f, h2 = 0.f, h11 = 0.f, h22 = 0.f, h12 = 0.f;
#pragma unroll
    for (int j = 0; j < P; ++j) {
      float a = ra[tid + j];
      float c = rb[tid + j];
      h1 += a;
      h2 += c;
      h11 = fmaf(a, a, h11);
      h22 = fmaf(c, c, h22);
      h12 = fmaf(a, c, h12);
    }
    __syncthreads();  // ra/rb free to overwrite next iteration

    int slot = t % 13;
    S1 += h1; S2 += h2; S11 += h11; S22 += h22; S12 += h12;
    if (t >= 13) {
      S1 -= ring[0][slot][tid];
      S2 -= ring[1][slot][tid];
      S11 -= ring[2][slot][tid];
      S22 -= ring[3][slot][tid];
      S12 -= ring[4][slot][tid];
    }
    ring[0][slot][tid] = h1;
    ring[1][slot][tid] = h2;
    ring[2][slot][tid] = h11;
    ring[3][slot][tid] = h22;
    ring[4][slot][tid] = h12;

    if (t >= 12 && valid) {
      float m1 = S1 * inv_n;
      float m2 = S2 * inv_n;
      float v1 = fmaf(-m1, m1, S11 * inv_n);
      float v2 = fmaf(-m2, m2, S22 * inv_n);
      float cross = fmaf(-S1 * inv_n, S2, S12);  // S12 - S1*S2/169
      acc += cross * rsqrtf((v1 + EPS) * (v2 + EPS));
    }
  }

  // 64-lane wave reduce (single wave per block)
#pragma unroll
  for (int off = 32; off > 0; off >>= 1) acc += __shfl_down(acc, off, 64);
  if (tid == 0) atomicAdd(&ps[b], acc);
}

// ---------------------------------------------------------------------------
// Kernel C: combine. out[b] = 0.5*global + 0.5*patch_sum/(HP*WP*169)
// ---------------------------------------------------------------------------
__global__ void final_kernel(const float* __restrict__ gs,
                             const float* __restrict__ ps,
                             float* __restrict__ out) {
  int b = threadIdx.x;
  if (b < B) {
    float Nf = (float)NPIX;
    float s1 = gs[0 * B + b];
    float s2 = gs[1 * B + b];
    float s11 = gs[2 * B + b];
    float s22 = gs[3 * B + b];
    float s12 = gs[4 * B + b];
    float m1 = s1 / Nf;
    float m2 = s2 / Nf;
    float v1 = fmaf(-m1, m1, s11 / Nf);
    float v2 = fmaf(-m2, m2, s22 / Nf);
    float cross = fmaf(-Nf * m1, m2, s12);
    float g = cross * rsqrtf((v1 + EPS) * (v2 + EPS)) / Nf;
    float patch = ps[b] / ((float)HP * (float)WP * 169.0f);
    out[b] = 0.5f * g + 0.5f * patch;
  }
}

extern "C" void kernel_launch(void* const* d_in, const int* in_sizes, int n_in,
                              void* d_out, int out_size, void* d_ws, size_t ws_size,
                              hipStream_t stream) {
  const float* x1 = (const float*)d_in[0];
  const float* x2 = (const float*)d_in[1];
  float* out = (float*)d_out;
  float* gs = (float*)d_ws;        // 5*B floats
  float* ps = gs + 5 * B;          // B floats

  hipMemsetAsync(d_ws, 0, 6 * B * sizeof(float), stream);

  global_stats_kernel<<<B * 8, 256, 0, stream>>>(x1, x2, gs);
  patch_kernel<<<B * TILES_X * BANDS_Y, 64, 0, stream>>>(x1, x2, ps);
  final_kernel<<<1, 64, 0, stream>>>(gs, ps, out);
}

// Round 2
// 157.626 us; speedup vs baseline: 1.3806x; 1.3806x over previous
//
#include <hip/hip_runtime.h>

#define EPS 1e-5f

constexpr int B = 32;
constexpr int H = 512;
constexpr int W = 512;
constexpr int NPIX = H * W;          // 262144
constexpr int P = 13;
constexpr int HP = H - P + 1;        // 500
constexpr int WP = W - P + 1;        // 500
constexpr int TILES_X = 8;           // 8 * 64 = 512 cols
constexpr int BANDS_Y = 10;          // 10 * 50 = 500 output rows
constexpr int BAND_ROWS = 50;
constexpr int ITERS = BAND_ROWS + P - 1;  // 62 input rows per band

// ws layout (floats): gs[5][B] global moment sums, then ps[B] patch cc sums

// ---------------------------------------------------------------------------
// Fused kernel: per block = (batch, 64-col tile, 50-row band), one wave.
//  - stages rows as interleaved float2 (a,b) into double-buffered LDS
//  - prefetches next row's globals into registers before the barrier
//  - 13-tap horizontal sums from 13 ds_read_b64
//  - vertical sliding sum via packed LDS ring (b128 + b32)
//  - accumulates GLOBAL moment sums over its owned (non-overlapping) region
//    during staging, so the separate global_stats pass is eliminated
// grid = 32*8*10 = 2560 blocks (~10 waves/CU)
// ---------------------------------------------------------------------------
__global__ __launch_bounds__(64) void patch_fused_kernel(
    const float* __restrict__ x1, const float* __restrict__ x2,
    float* __restrict__ gs, float* __restrict__ ps) {
  int bid = blockIdx.x;
  int b = bid / (TILES_X * BANDS_Y);
  int rem = bid % (TILES_X * BANDS_Y);
  int tile = rem % TILES_X;
  int band = rem / TILES_X;
  int x0 = tile * 64;
  int y0 = band * BAND_ROWS;
  int tid = threadIdx.x;
  bool valid = (x0 + tid) < WP;
  bool last_band = (band == BANDS_Y - 1);

  __shared__ float2 st[2][80];        // double-buffered row stage (76 used)
  __shared__ float4 ring4[13][64];    // h1,h2,h11,h22
  __shared__ float ring5[13][64];     // h12

  const float* b1 = x1 + (size_t)b * NPIX;
  const float* b2 = x2 + (size_t)b * NPIX;

  int c = x0 + tid;                       // always in [0,511]
  int ch = min(x0 + 64 + tid, W - 1);     // halo column (clamped; unused cols masked later)

  // prologue: load row y0 into registers
  float a = b1[y0 * W + c];
  float bb = b2[y0 * W + c];
  float ah = 0.f, bh = 0.f;
  if (tid < 12) { ah = b1[y0 * W + ch]; bh = b2[y0 * W + ch]; }

  float4 S4 = {0.f, 0.f, 0.f, 0.f};   // sliding window: s1,s2,s11,s22
  float S5 = 0.f;                      // s12
  float g1 = 0.f, g2 = 0.f, g11 = 0.f, g22 = 0.f, g12 = 0.f;  // global moments
  float acc = 0.f;
  const float inv_n = 1.0f / 169.0f;

  for (int t = 0; t < ITERS; ++t) {
    // --- global-stats accumulation over owned region (lanes 0..63 cols only,
    //     owned rows: first 50 for bands 0..8, all 62 for band 9) ---
    bool owned = last_band | (t < BAND_ROWS);
    if (owned) {
      g1 += a; g2 += bb;
      g11 = fmaf(a, a, g11); g22 = fmaf(bb, bb, g22); g12 = fmaf(a, bb, g12);
    }

    // --- stage current row (interleaved) ---
    int buf = t & 1;
    st[buf][tid] = make_float2(a, bb);
    if (tid < 12) st[buf][64 + tid] = make_float2(ah, bh);
    __syncthreads();

    // --- prefetch next row into registers (latency hidden behind compute) ---
    if (t < ITERS - 1) {
      int yy = y0 + t + 1;
      a = b1[yy * W + c];
      bb = b2[yy * W + c];
      if (tid < 12) { ah = b1[yy * W + ch]; bh = b2[yy * W + ch]; }
    }

    // --- horizontal 13-tap sums (13 x ds_read_b64, imm offsets) ---
    float h1 = 0.f, h2 = 0.f, h11 = 0.f, h22 = 0.f, h12 = 0.f;
#pragma unroll
    for (int j = 0; j < P; ++j) {
      float2 v = st[buf][tid + j];
      h1 += v.x;
      h2 += v.y;
      h11 = fmaf(v.x, v.x, h11);
      h22 = fmaf(v.y, v.y, h22);
      h12 = fmaf(v.x, v.y, h12);
    }

    // --- vertical sliding sum via packed ring ---
    int slot = t % 13;
    S4.x += h1; S4.y += h2; S4.z += h11; S4.w += h22; S5 += h12;
    if (t >= 13) {
      float4 o = ring4[slot][tid];
      float o5 = ring5[slot][tid];
      S4.x -= o.x; S4.y -= o.y; S4.z -= o.z; S4.w -= o.w; S5 -= o5;
    }
    ring4[slot][tid] = make_float4(h1, h2, h11, h22);
    ring5[slot][tid] = h12;

    // --- epilogue: local NCC for output row y0 + t - 12 ---
    if (t >= 12) {
      float m1 = S4.x * inv_n;
      float m2 = S4.y * inv_n;
      float v1 = fmaf(-m1, m1, S4.z * inv_n);
      float v2 = fmaf(-m2, m2, S4.w * inv_n);
      float cross = fmaf(-S4.x * inv_n, S4.y, S5);
      float cc = cross * rsqrtf((v1 + EPS) * (v2 + EPS));
      acc += valid ? cc : 0.f;
    }
  }

  // --- wave reductions (single wave per block) + atomics ---
#pragma unroll
  for (int off = 32; off > 0; off >>= 1) {
    acc += __shfl_down(acc, off, 64);
    g1 += __shfl_down(g1, off, 64);
    g2 += __shfl_down(g2, off, 64);
    g11 += __shfl_down(g11, off, 64);
    g22 += __shfl_down(g22, off, 64);
    g12 += __shfl_down(g12, off, 64);
  }
  if (tid == 0) {
    atomicAdd(&ps[b], acc);
    atomicAdd(&gs[0 * B + b], g1);
    atomicAdd(&gs[1 * B + b], g2);
    atomicAdd(&gs[2 * B + b], g11);
    atomicAdd(&gs[3 * B + b], g22);
    atomicAdd(&gs[4 * B + b], g12);
  }
}

// ---------------------------------------------------------------------------
// Combine: out[b] = 0.5*global_ncc + 0.5*patch_sum/(HP*WP*169)
// ---------------------------------------------------------------------------
__global__ void final_kernel(const float* __restrict__ gs,
                             const float* __restrict__ ps,
                             float* __restrict__ out) {
  int b = threadIdx.x;
  if (b < B) {
    float Nf = (float)NPIX;
    float s1 = gs[0 * B + b];
    float s2 = gs[1 * B + b];
    float s11 = gs[2 * B + b];
    float s22 = gs[3 * B + b];
    float s12 = gs[4 * B + b];
    float m1 = s1 / Nf;
    float m2 = s2 / Nf;
    float v1 = fmaf(-m1, m1, s11 / Nf);
    float v2 = fmaf(-m2, m2, s22 / Nf);
    float cross = fmaf(-Nf * m1, m2, s12);
    float g = cross * rsqrtf((v1 + EPS) * (v2 + EPS)) / Nf;
    float patch = ps[b] / ((float)HP * (float)WP * 169.0f);
    out[b] = 0.5f * g + 0.5f * patch;
  }
}

extern "C" void kernel_launch(void* const* d_in, const int* in_sizes, int n_in,
                              void* d_out, int out_size, void* d_ws, size_t ws_size,
                              hipStream_t stream) {
  const float* x1 = (const float*)d_in[0];
  const float* x2 = (const float*)d_in[1];
  float* out = (float*)d_out;
  float* gs = (float*)d_ws;        // 5*B floats
  float* ps = gs + 5 * B;          // B floats

  hipMemsetAsync(d_ws, 0, 6 * B * sizeof(float), stream);

  patch_fused_kernel<<<B * TILES_X * BANDS_Y, 64, 0, stream>>>(x1, x2, gs, ps);
  final_kernel<<<1, 64, 0, stream>>>(gs, ps, out);
}